// Round 8
// baseline (1287.876 us; speedup 1.0000x reference)
//
#include <hip/hip_runtime.h>
#include <hip/hip_bf16.h>
#include <math.h>

#define Bsz 1024
#define Nn  11
#define Ff  512
#define Zi  10
#define G3  1536

#define PE   528    // E plane stride: 32 rows * 16B + 16 pad
#define PW   8224   // link W plane stride: 512 cols * 16B + 32 pad
#define PLA  1056   // gates A plane stride (64 rows * 16B + 32 pad)
#define PGW2 2080   // gates W plane stride (128 g * 16B + 32 pad)

typedef __attribute__((ext_vector_type(8))) short bfrag;
typedef __attribute__((ext_vector_type(16))) float f32x16;

__device__ __forceinline__ unsigned f2bf(float f) {
    __hip_bfloat16 h = __float2bfloat16(f);
    return (unsigned)*reinterpret_cast<unsigned short*>(&h);
}
__device__ __forceinline__ uint4 pack8(float v0, float v1, float v2, float v3,
                                       float v4, float v5, float v6, float v7) {
    uint4 pk;
    pk.x = f2bf(v0) | (f2bf(v1) << 16);
    pk.y = f2bf(v2) | (f2bf(v3) << 16);
    pk.z = f2bf(v4) | (f2bf(v5) << 16);
    pk.w = f2bf(v6) | (f2bf(v7) << 16);
    return pk;
}
__device__ __forceinline__ void pair_decode(int mode, int p, int& pi, int& pj) {
    if (mode == 0) { int r = p, i = 0; while (r >= Nn - i) { r -= Nn - i; ++i; } pi = i; pj = i + r; }
    else { pi = p; pj = Zi; }
}

// ---------------------------------------------------------------------------
__global__ void init_col_kernel(const float* __restrict__ nf, float* __restrict__ col) {
    int idx = blockIdx.x * 256 + threadIdx.x;
    int b = idx >> 9, f = idx & 511;
    col[idx] = nf[(b * Nn + Zi) * Ff + f];
}

__global__ void convert_bf16_kernel(const float* __restrict__ src,
                                    unsigned short* __restrict__ dst) {
    int i = blockIdx.x * 256 + threadIdx.x;
    dst[i] = (unsigned short)f2bf(src[i]);
}

// ---------------------------------------------------------------------------
// Fused link MLP. Block = 32 rows (1 pair x 32 batches) x all 512 cols.
// 512 thr / 8 waves; wave tile 32x64 (acc0,acc1 = 32 VGPR).
// E: 64 planes (8 k each) x 32 rows, conflict-free, resident; h1 in-place.
// W: single-buffered 4-plane slice (32 k), loads issued at ks-top (latency
// hidden under MFMA), 2 barriers per ks. 2 blocks/CU co-resident.
// ---------------------------------------------------------------------------
__global__ __launch_bounds__(512, 4) void link_kernel(
    const float* __restrict__ nf, const float* __restrict__ colp,
    const unsigned short* __restrict__ W1bf, const float* __restrict__ b1,
    const unsigned short* __restrict__ W2bf, const float* __restrict__ b2,
    const float* __restrict__ w_out, const float* __restrict__ b_out,
    float* __restrict__ adj, int mode)
{
    __shared__ char Eb[64 * PE];     // 33,792 B
    __shared__ char Wb[4 * PW];      // 32,896 B
    __shared__ float Pl[8][32];

    const int tid = threadIdx.x;
    const int pr  = blockIdx.x >> 5;
    const int bc  = blockIdx.x & 31;
    int pi, pj; pair_decode(mode, pr, pi, pj);

    // ---- W1 slice-0 loads issued first (hide under E build) ----
    uint4 wreg[4];
#pragma unroll
    for (int i = 0; i < 4; ++i) {
        int c = i * 512 + tid;
        int col = c >> 2, kq = c & 3;
        wreg[i] = *(const uint4*)(W1bf + col * Ff + kq * 8);
    }

    // ---- E build: plane p (k = p*8..p*8+7), rows 0..31 ----
#pragma unroll
    for (int i = 0; i < 4; ++i) {
        int c = i * 512 + tid;
        int p = c >> 5, r = c & 31;
        int b = bc * 32 + r;
        const float* xi = (pi == Zi) ? (colp + b * Ff) : (nf + (b * Nn + pi) * Ff);
        const float* xj = (pj == Zi) ? (colp + b * Ff) : (nf + (b * Nn + pj) * Ff);
        const float* pxi = xi + p * 8;
        const float* pxj = xj + p * 8;
        float4 u0 = *(const float4*)pxi, u1 = *(const float4*)(pxi + 4);
        float4 v0 = *(const float4*)pxj, v1 = *(const float4*)(pxj + 4);
        uint4 pk = pack8(u0.x*v0.x, u0.y*v0.y, u0.z*v0.z, u0.w*v0.w,
                         u1.x*v1.x, u1.y*v1.y, u1.z*v1.z, u1.w*v1.w);
        *(uint4*)(&Eb[p * PE + r * 16]) = pk;
    }

    // ---- store W slice 0 ----
#pragma unroll
    for (int i = 0; i < 4; ++i) {
        int c = i * 512 + tid;
        int col = c >> 2, kq = c & 3;
        *(uint4*)(&Wb[kq * PW + col * 16]) = wreg[i];
    }
    __syncthreads();

    const int wid = tid >> 6;
    const int l   = tid & 63;
    const int lr  = l & 31;
    const int kg  = l >> 5;
    const int col0 = wid * 64 + lr;
    const int col1 = col0 + 32;

    f32x16 acc0, acc1;

#pragma unroll 1
    for (int lay = 0; lay < 2; ++lay) {
        const unsigned short* W = lay ? W2bf : W1bf;
        acc0 = (f32x16)(0.f);
        acc1 = (f32x16)(0.f);

#pragma unroll 1
        for (int ks = 0; ks < 16; ++ks) {
            const bool pre = (ks < 15) || (lay == 0);
            if (pre) {
                const unsigned short* Ws = (ks < 15) ? W : W2bf;
                const int k0 = (ks < 15) ? (ks + 1) * 32 : 0;
#pragma unroll
                for (int i = 0; i < 4; ++i) {
                    int c = i * 512 + tid;
                    int col = c >> 2, kq = c & 3;
                    wreg[i] = *(const uint4*)(Ws + col * Ff + k0 + kq * 8);
                }
            }
#pragma unroll
            for (int s = 0; s < 2; ++s) {
                const int wp = 2 * s + kg;
                bfrag a  = *(const bfrag*)(&Eb[(ks * 4 + wp) * PE + lr * 16]);
                bfrag w0 = *(const bfrag*)(&Wb[wp * PW + col0 * 16]);
                bfrag w1 = *(const bfrag*)(&Wb[wp * PW + col1 * 16]);
                acc0 = __builtin_amdgcn_mfma_f32_32x32x16_bf16(a, w0, acc0, 0, 0, 0);
                acc1 = __builtin_amdgcn_mfma_f32_32x32x16_bf16(a, w1, acc1, 0, 0, 0);
            }
            __syncthreads();            // all Wb (and, at ks=15, Eb) reads done
            if (pre) {
#pragma unroll
                for (int i = 0; i < 4; ++i) {
                    int c = i * 512 + tid;
                    int col = c >> 2, kq = c & 3;
                    *(uint4*)(&Wb[kq * PW + col * 16]) = wreg[i];
                }
            }
            if (lay == 0 && ks == 15) {
                // h1 = relu(acc + b1) -> Eb in place (E fully consumed)
                float bv0 = b1[col0], bv1 = b1[col1];
#pragma unroll
                for (int reg = 0; reg < 16; ++reg) {
                    int row = (reg & 3) + 8 * (reg >> 2) + 4 * kg;
                    float v0 = fmaxf(acc0[reg] + bv0, 0.f);
                    float v1 = fmaxf(acc1[reg] + bv1, 0.f);
                    *(unsigned short*)(&Eb[(col0 >> 3) * PE + row * 16 + (col0 & 7) * 2]) =
                        (unsigned short)f2bf(v0);
                    *(unsigned short*)(&Eb[(col1 >> 3) * PE + row * 16 + (col1 & 7) * 2]) =
                        (unsigned short)f2bf(v1);
                }
            }
            __syncthreads();            // Wb/Eb writes visible
        }
    }

    // ---- fused layer-3: rowsum of relu(acc+b2)*w_out ----
    {
        float bv0 = b2[col0], bv1 = b2[col1];
        float wv0 = w_out[col0], wv1 = w_out[col1];
        float rs[16];
#pragma unroll
        for (int reg = 0; reg < 16; ++reg)
            rs[reg] = fmaxf(acc0[reg] + bv0, 0.f) * wv0
                    + fmaxf(acc1[reg] + bv1, 0.f) * wv1;
#pragma unroll
        for (int off = 1; off < 32; off <<= 1)
#pragma unroll
            for (int reg = 0; reg < 16; ++reg)
                rs[reg] += __shfl_xor(rs[reg], off);
        if (lr == 0) {
#pragma unroll
            for (int reg = 0; reg < 16; ++reg) {
                int row = (reg & 3) + 8 * (reg >> 2) + 4 * kg;
                Pl[wid][row] = rs[reg];
            }
        }
    }
    __syncthreads();
    if (tid < 32) {
        float v = b_out[0];
#pragma unroll
        for (int w = 0; w < 8; ++w) v += Pl[w][tid];
        int b = bc * 32 + tid;
        adj[b * (Nn * Nn) + pi * Nn + pj] = v;
        if (pi != pj) adj[b * (Nn * Nn) + pj * Nn + pi] = v;
    }
}

// ---------------------------------------------------------------------------
__global__ void softmax_az_kernel(const float* __restrict__ adj, float* __restrict__ a_z) {
    int b = blockIdx.x * 256 + threadIdx.x;
    if (b >= Bsz) return;
    const float* row = adj + b * (Nn * Nn) + Zi * Nn;
    float mx = row[0];
#pragma unroll
    for (int j = 1; j < Nn; ++j) mx = fmaxf(mx, row[j]);
    float e[Nn]; float s = 0.f;
#pragma unroll
    for (int j = 0; j < Nn; ++j) { e[j] = expf(row[j] - mx); s += e[j]; }
    float inv = 1.f / s;
#pragma unroll
    for (int j = 0; j < Nn; ++j) a_z[b * Nn + j] = e[j] * inv;
}

__global__ void mfix_kernel(const float* __restrict__ nf, const float* __restrict__ a_z,
                            float* __restrict__ m_fix) {
    int idx = blockIdx.x * 256 + threadIdx.x;
    int b = idx >> 9, f = idx & 511;
    float s = 0.f;
#pragma unroll
    for (int j = 0; j < Nn - 1; ++j)
        s += a_z[b * Nn + j] * nf[(b * Nn + j) * Ff + f];
    m_fix[idx] = s;
}

// ---------------------------------------------------------------------------
// gates: gi = (m_fix + az*col) @ Wih^T ; gh = col @ Whh^T (fp32 out)
// ---------------------------------------------------------------------------
__global__ __launch_bounds__(256, 3) void gates_kernel(
    const float* __restrict__ m_fix, const float* __restrict__ a_z,
    const float* __restrict__ colp,
    const unsigned short* __restrict__ Wih, const unsigned short* __restrict__ Whh,
    float* __restrict__ gi, float* __restrict__ gh)
{
    __shared__ char Wb[2][4 * PGW2];
    __shared__ char Ab[2][4 * PLA];

    const int xb = blockIdx.x, bc = blockIdx.y, tid = threadIdx.x;
    const bool isGi = xb < 12;
    const int nbase = (isGi ? xb : xb - 12) * 128;
    const unsigned short* W = isGi ? Wih : Whh;
    float* C = isGi ? gi : gh;

    const int bloc = tid >> 2;
    const int kc   = tid & 3;
    const int b    = bc * 64 + bloc;
    const float* cs = colp + b * Ff;
    const float* mf = m_fix + b * Ff;
    const float azv = isGi ? a_z[b * Nn + Zi] : 0.f;

    uint4 wreg[2];
    uint4 areg;

    auto loadA = [&](int k0) {
        const float* pc = cs + k0 + kc * 8;
        float4 c0 = *(const float4*)pc, c1 = *(const float4*)(pc + 4);
        if (isGi) {
            const float* pm = mf + k0 + kc * 8;
            float4 m0 = *(const float4*)pm, m1 = *(const float4*)(pm + 4);
            areg = pack8(m0.x + azv*c0.x, m0.y + azv*c0.y, m0.z + azv*c0.z, m0.w + azv*c0.w,
                         m1.x + azv*c1.x, m1.y + azv*c1.y, m1.z + azv*c1.z, m1.w + azv*c1.w);
        } else {
            areg = pack8(c0.x, c0.y, c0.z, c0.w, c1.x, c1.y, c1.z, c1.w);
        }
    };

    loadA(0);
#pragma unroll
    for (int i = 0; i < 2; ++i) {
        int chunk = i * 256 + tid;
        wreg[i] = *(const uint4*)(W + (nbase + (chunk >> 2)) * Ff + (chunk & 3) * 8);
    }
#pragma unroll
    for (int i = 0; i < 2; ++i) {
        int chunk = i * 256 + tid;
        *(uint4*)(&Wb[0][(chunk & 3) * PGW2 + (chunk >> 2) * 16]) = wreg[i];
    }
    *(uint4*)(&Ab[0][kc * PLA + bloc * 16]) = areg;
    __syncthreads();

    const int l  = tid & 63;
    const int nw = tid >> 6;
    const int lr = l & 31;
    const int kg = l >> 5;

    f32x16 acc[2];
    acc[0] = (f32x16)(0.f);
    acc[1] = (f32x16)(0.f);

#pragma unroll 1
    for (int ks = 0; ks < 16; ++ks) {
        const int cur = ks & 1;
        if (ks < 15) {
            const int k0 = (ks + 1) * 32;
            loadA(k0);
#pragma unroll
            for (int i = 0; i < 2; ++i) {
                int chunk = i * 256 + tid;
                wreg[i] = *(const uint4*)(W + (nbase + (chunk >> 2)) * Ff + k0 + (chunk & 3) * 8);
            }
        }
#pragma unroll
        for (int s = 0; s < 2; ++s) {
            const int kcv = 2 * s + kg;
            bfrag a0 = *(const bfrag*)(&Ab[cur][kcv * PLA + lr * 16]);
            bfrag a1 = *(const bfrag*)(&Ab[cur][kcv * PLA + (32 + lr) * 16]);
            bfrag bf = *(const bfrag*)(&Wb[cur][kcv * PGW2 + (nw * 32 + lr) * 16]);
            acc[0] = __builtin_amdgcn_mfma_f32_32x32x16_bf16(a0, bf, acc[0], 0, 0, 0);
            acc[1] = __builtin_amdgcn_mfma_f32_32x32x16_bf16(a1, bf, acc[1], 0, 0, 0);
        }
        if (ks < 15) {
#pragma unroll
            for (int i = 0; i < 2; ++i) {
                int chunk = i * 256 + tid;
                *(uint4*)(&Wb[cur ^ 1][(chunk & 3) * PGW2 + (chunk >> 2) * 16]) = wreg[i];
            }
            *(uint4*)(&Ab[cur ^ 1][kc * PLA + bloc * 16]) = areg;
        }
        __syncthreads();
    }

    const int colg = nbase + nw * 32 + lr;
#pragma unroll
    for (int m = 0; m < 2; ++m) {
#pragma unroll
        for (int reg = 0; reg < 16; ++reg) {
            int row = m * 32 + (reg & 3) + 8 * (reg >> 2) + 4 * kg;
            C[(bc * 64 + row) * G3 + colg] = acc[m][reg];
        }
    }
}

// ---------------------------------------------------------------------------
__global__ void gru_kernel(const float* __restrict__ gi, const float* __restrict__ gh,
                           float* __restrict__ col) {
    int idx = blockIdx.x * 256 + threadIdx.x;   // 4 f per thread
    int b = idx >> 7, f = (idx & 127) * 4;
    const float* gib = gi + b * G3;
    const float* ghb = gh + b * G3;
    float4 ir = *(const float4*)(gib + f);
    float4 iz = *(const float4*)(gib + Ff + f);
    float4 in = *(const float4*)(gib + 2 * Ff + f);
    float4 hr = *(const float4*)(ghb + f);
    float4 hz = *(const float4*)(ghb + Ff + f);
    float4 hn = *(const float4*)(ghb + 2 * Ff + f);
    float4 h  = *(const float4*)(col + b * Ff + f);
    float4 o;
#define GRU1(c) { \
    float r = 1.f / (1.f + expf(-(ir.c + hr.c))); \
    float z = 1.f / (1.f + expf(-(iz.c + hz.c))); \
    float n = tanhf(in.c + r * hn.c); \
    o.c = (1.f - z) * n + z * h.c; }
    GRU1(x) GRU1(y) GRU1(z) GRU1(w)
#undef GRU1
    *(float4*)(col + b * Ff + f) = o;
}

// ---------------------------------------------------------------------------
extern "C" void kernel_launch(void* const* d_in, const int* in_sizes, int n_in,
                              void* d_out, int out_size, void* d_ws, size_t ws_size,
                              hipStream_t stream) {
    const float* nf    = (const float*)d_in[0];
    const float* W1    = (const float*)d_in[1];
    const float* b1    = (const float*)d_in[2];
    const float* W2    = (const float*)d_in[3];
    const float* b2    = (const float*)d_in[4];
    const float* w_out = (const float*)d_in[5];
    const float* b_out = (const float*)d_in[6];
    const float* W_ih  = (const float*)d_in[7];
    const float* W_hh  = (const float*)d_in[8];

    float* adj = (float*)d_out;                 // (B, 11, 11)
    float* col = adj + Bsz * Nn * Nn;           // (B, 512)

    unsigned short* W1bf  = (unsigned short*)d_ws;
    unsigned short* W2bf  = W1bf + Ff * Ff;
    unsigned short* Wihbf = W2bf + Ff * Ff;
    unsigned short* Whhbf = Wihbf + G3 * Ff;
    float* a_z   = (float*)(Whhbf + G3 * Ff);
    float* m_fix = a_z + 16384;
    float* gi    = m_fix + Bsz * Ff;
    float* gh    = gi + Bsz * G3;

    init_col_kernel<<<(Bsz * Ff) / 256, 256, 0, stream>>>(nf, col);
    convert_bf16_kernel<<<(Ff * Ff) / 256, 256, 0, stream>>>(W1, W1bf);
    convert_bf16_kernel<<<(Ff * Ff) / 256, 256, 0, stream>>>(W2, W2bf);
    convert_bf16_kernel<<<(G3 * Ff) / 256, 256, 0, stream>>>(W_ih, Wihbf);
    convert_bf16_kernel<<<(G3 * Ff) / 256, 256, 0, stream>>>(W_hh, Whhbf);

    for (int t = 0; t < 3; ++t) {
        const int mode   = (t == 0) ? 0 : 1;
        const int npairs = (t == 0) ? 66 : 11;

        link_kernel<<<npairs * 32, 512, 0, stream>>>(nf, col, W1bf, b1, W2bf, b2,
                                                     w_out, b_out, adj, mode);
        softmax_az_kernel<<<Bsz / 256, 256, 0, stream>>>(adj, a_z);
        mfix_kernel<<<(Bsz * Ff) / 256, 256, 0, stream>>>(nf, a_z, m_fix);

        for (int s = 0; s < 3; ++s) {
            gates_kernel<<<dim3(24, 16), 256, 0, stream>>>(m_fix, a_z, col,
                                                           Wihbf, Whhbf, gi, gh);
            gru_kernel<<<(Bsz * Ff) / 4 / 256, 256, 0, stream>>>(gi, gh, col);
        }
    }
}

// Round 9
// 713.248 us; speedup vs baseline: 1.8056x; 1.8056x over previous
//
#include <hip/hip_runtime.h>
#include <hip/hip_bf16.h>
#include <math.h>

#define Bsz 1024
#define Nn  11
#define Ff  512
#define Zi  10
#define G3  1536

#define PE   1056   // E plane stride: 64 rows * 16B + 32 pad
#define PLA  1056   // gates A plane stride (64 rows * 16B + 32 pad)
#define PGW2 2080   // gates W plane stride (128 g * 16B + 32 pad)

typedef __attribute__((ext_vector_type(8))) short bfrag;
typedef __attribute__((ext_vector_type(16))) float f32x16;

__device__ __forceinline__ unsigned f2bf(float f) {
    __hip_bfloat16 h = __float2bfloat16(f);
    return (unsigned)*reinterpret_cast<unsigned short*>(&h);
}
__device__ __forceinline__ uint4 pack8(float v0, float v1, float v2, float v3,
                                       float v4, float v5, float v6, float v7) {
    uint4 pk;
    pk.x = f2bf(v0) | (f2bf(v1) << 16);
    pk.y = f2bf(v2) | (f2bf(v3) << 16);
    pk.z = f2bf(v4) | (f2bf(v5) << 16);
    pk.w = f2bf(v6) | (f2bf(v7) << 16);
    return pk;
}
__device__ __forceinline__ void pair_decode(int mode, int p, int& pi, int& pj) {
    if (mode == 0) { int r = p, i = 0; while (r >= Nn - i) { r -= Nn - i; ++i; } pi = i; pj = i + r; }
    else { pi = p; pj = Zi; }
}
// async global->LDS, 16B/lane; dst is wave-uniform base (+lane*16 by HW)
__device__ __forceinline__ void gl_lds16(const void* src, void* dst) {
    __builtin_amdgcn_global_load_lds((const __attribute__((address_space(1))) void*)src,
                                     (__attribute__((address_space(3))) void*)dst, 16, 0, 0);
}

// ---------------------------------------------------------------------------
__global__ void init_col_kernel(const float* __restrict__ nf, float* __restrict__ col) {
    int idx = blockIdx.x * 256 + threadIdx.x;
    int b = idx >> 9, f = idx & 511;
    col[idx] = nf[(b * Nn + Zi) * Ff + f];
}

__global__ void convert_bf16_kernel(const float* __restrict__ src,
                                    unsigned short* __restrict__ dst) {
    int i = blockIdx.x * 256 + threadIdx.x;
    dst[i] = (unsigned short)f2bf(src[i]);
}

// ---------------------------------------------------------------------------
// Fused link MLP. Block = 64 rows (1 pair x 64 batches) x all 512 cols.
// 512 thr / 8 waves; wave tile 64x64 (acc[2][2] = 64 VGPR).
// E: 64 planes (8 k) x 64 rows, conflict-free, resident; h1 in-place.
// W: double-buffered 32KB K-slice staged via global_load_lds (NO staging
// VGPRs -> nothing to spill); one barrier per ks (vmcnt drains there).
// ---------------------------------------------------------------------------
__global__ __launch_bounds__(512, 2) void link_kernel(
    const float* __restrict__ nf, const float* __restrict__ colp,
    const unsigned short* __restrict__ W1bf, const float* __restrict__ b1,
    const unsigned short* __restrict__ W2bf, const float* __restrict__ b2,
    const float* __restrict__ w_out, const float* __restrict__ b_out,
    float* __restrict__ adj, int mode)
{
    __shared__ char  Eb[64 * PE];        // 67,584 B
    __shared__ char  Wb[2][4 * 8192];    // 65,536 B (4 planes x 512 cols x 16B)
    __shared__ float Pl[8][64];          //  2,048 B

    const int tid = threadIdx.x;
    const int pr  = blockIdx.x >> 4;
    const int bc  = blockIdx.x & 15;
    int pi, pj; pair_decode(mode, pr, pi, pj);

    const int wid = tid >> 6;
    const int l   = tid & 63;
    const int lr  = l & 31;
    const int kg  = l >> 5;

    // ---- issue W1 slice-0 (async, no regs) ----
#pragma unroll
    for (int i = 0; i < 4; ++i) {
        int c   = (wid * 4 + i) * 64;          // chunk base (lane adds +l)
        int kq  = c >> 9;
        int col = (c & 511) + l;
        gl_lds16(W1bf + col * Ff + kq * 8, (char*)Wb[0] + c * 16);
    }

    // ---- E build: plane l holds k = l*8..l*8+7; coalesced 32B/lane reads ----
#pragma unroll
    for (int rr = 0; rr < 8; ++rr) {
        int r = wid * 8 + rr;
        int b = bc * 64 + r;
        const float* xi = (pi == Zi) ? (colp + b * Ff) : (nf + (b * Nn + pi) * Ff);
        const float* xj = (pj == Zi) ? (colp + b * Ff) : (nf + (b * Nn + pj) * Ff);
        const float* pxi = xi + l * 8;
        const float* pxj = xj + l * 8;
        float4 u0 = *(const float4*)pxi, u1 = *(const float4*)(pxi + 4);
        float4 v0 = *(const float4*)pxj, v1 = *(const float4*)(pxj + 4);
        uint4 pk = pack8(u0.x*v0.x, u0.y*v0.y, u0.z*v0.z, u0.w*v0.w,
                         u1.x*v1.x, u1.y*v1.y, u1.z*v1.z, u1.w*v1.w);
        *(uint4*)(&Eb[l * PE + r * 16]) = pk;
    }
    __syncthreads();    // drains gl_lds (vmcnt) + Eb writes

    f32x16 acc[2][2];
#pragma unroll
    for (int m = 0; m < 2; ++m)
#pragma unroll
        for (int n = 0; n < 2; ++n) acc[m][n] = (f32x16)(0.f);

#pragma unroll 1
    for (int gks = 0; gks < 32; ++gks) {
        const int ks  = gks & 15;
        const int cur = gks & 1;
        if (gks < 31) {
            const unsigned short* Ws = (gks >= 15) ? W2bf : W1bf;
            const int k0 = ((gks + 1) & 15) * 32;
#pragma unroll
            for (int i = 0; i < 4; ++i) {
                int c   = (wid * 4 + i) * 64;
                int kq  = c >> 9;
                int col = (c & 511) + l;
                gl_lds16(Ws + col * Ff + k0 + kq * 8, (char*)Wb[cur ^ 1] + c * 16);
            }
        }
        const char* Wc = (const char*)Wb[cur];
#pragma unroll
        for (int s = 0; s < 2; ++s) {
            const int kcv   = 2 * s + kg;
            const int plane = ks * 4 + kcv;
            bfrag a0 = *(const bfrag*)(&Eb[plane * PE + lr * 16]);
            bfrag a1 = *(const bfrag*)(&Eb[plane * PE + (32 + lr) * 16]);
            bfrag w0 = *(const bfrag*)(Wc + kcv * 8192 + (wid * 64 + lr) * 16);
            bfrag w1 = *(const bfrag*)(Wc + kcv * 8192 + (wid * 64 + 32 + lr) * 16);
            acc[0][0] = __builtin_amdgcn_mfma_f32_32x32x16_bf16(a0, w0, acc[0][0], 0, 0, 0);
            acc[0][1] = __builtin_amdgcn_mfma_f32_32x32x16_bf16(a0, w1, acc[0][1], 0, 0, 0);
            acc[1][0] = __builtin_amdgcn_mfma_f32_32x32x16_bf16(a1, w0, acc[1][0], 0, 0, 0);
            acc[1][1] = __builtin_amdgcn_mfma_f32_32x32x16_bf16(a1, w1, acc[1][1], 0, 0, 0);
        }
        __syncthreads();   // Wb[cur^1] staged + all Wb[cur]/Eb reads done

        if (gks == 15) {
            // h1 = relu(acc + b1) -> Eb in place (E fully consumed)
#pragma unroll
            for (int n = 0; n < 2; ++n) {
                int c = wid * 64 + n * 32 + lr;
                float bv = b1[c];
#pragma unroll
                for (int m = 0; m < 2; ++m)
#pragma unroll
                    for (int reg = 0; reg < 16; ++reg) {
                        int row = m * 32 + (reg & 3) + 8 * (reg >> 2) + 4 * kg;
                        float v = fmaxf(acc[m][n][reg] + bv, 0.f);
                        *(unsigned short*)(&Eb[(c >> 3) * PE + row * 16 + (c & 7) * 2]) =
                            (unsigned short)f2bf(v);
                    }
            }
#pragma unroll
            for (int m = 0; m < 2; ++m)
#pragma unroll
                for (int n = 0; n < 2; ++n) acc[m][n] = (f32x16)(0.f);
            __syncthreads();
        }
    }

    // ---- fused layer-3: rowsum of relu(acc+b2)*w_out ----
    {
        float rs[2][16];
#pragma unroll
        for (int m = 0; m < 2; ++m)
#pragma unroll
            for (int reg = 0; reg < 16; ++reg) rs[m][reg] = 0.f;
#pragma unroll
        for (int n = 0; n < 2; ++n) {
            int c = wid * 64 + n * 32 + lr;
            float bv = b2[c];
            float wv = w_out[c];
#pragma unroll
            for (int m = 0; m < 2; ++m)
#pragma unroll
                for (int reg = 0; reg < 16; ++reg)
                    rs[m][reg] += fmaxf(acc[m][n][reg] + bv, 0.f) * wv;
        }
#pragma unroll
        for (int off = 1; off < 32; off <<= 1)
#pragma unroll
            for (int m = 0; m < 2; ++m)
#pragma unroll
                for (int reg = 0; reg < 16; ++reg)
                    rs[m][reg] += __shfl_xor(rs[m][reg], off);
        if (lr == 0) {
#pragma unroll
            for (int m = 0; m < 2; ++m)
#pragma unroll
                for (int reg = 0; reg < 16; ++reg) {
                    int row = m * 32 + (reg & 3) + 8 * (reg >> 2) + 4 * kg;
                    Pl[wid][row] = rs[m][reg];
                }
        }
    }
    __syncthreads();
    if (tid < 64) {
        float v = b_out[0];
#pragma unroll
        for (int w = 0; w < 8; ++w) v += Pl[w][tid];
        int b = bc * 64 + tid;
        adj[b * (Nn * Nn) + pi * Nn + pj] = v;
        if (pi != pj) adj[b * (Nn * Nn) + pj * Nn + pi] = v;
    }
}

// ---------------------------------------------------------------------------
__global__ void softmax_az_kernel(const float* __restrict__ adj, float* __restrict__ a_z) {
    int b = blockIdx.x * 256 + threadIdx.x;
    if (b >= Bsz) return;
    const float* row = adj + b * (Nn * Nn) + Zi * Nn;
    float mx = row[0];
#pragma unroll
    for (int j = 1; j < Nn; ++j) mx = fmaxf(mx, row[j]);
    float e[Nn]; float s = 0.f;
#pragma unroll
    for (int j = 0; j < Nn; ++j) { e[j] = expf(row[j] - mx); s += e[j]; }
    float inv = 1.f / s;
#pragma unroll
    for (int j = 0; j < Nn; ++j) a_z[b * Nn + j] = e[j] * inv;
}

__global__ void mfix_kernel(const float* __restrict__ nf, const float* __restrict__ a_z,
                            float* __restrict__ m_fix) {
    int idx = blockIdx.x * 256 + threadIdx.x;
    int b = idx >> 9, f = idx & 511;
    float s = 0.f;
#pragma unroll
    for (int j = 0; j < Nn - 1; ++j)
        s += a_z[b * Nn + j] * nf[(b * Nn + j) * Ff + f];
    m_fix[idx] = s;
}

// ---------------------------------------------------------------------------
// gates: gi = (m_fix + az*col) @ Wih^T ; gh = col @ Whh^T (fp32 out)
// ---------------------------------------------------------------------------
__global__ __launch_bounds__(256, 3) void gates_kernel(
    const float* __restrict__ m_fix, const float* __restrict__ a_z,
    const float* __restrict__ colp,
    const unsigned short* __restrict__ Wih, const unsigned short* __restrict__ Whh,
    float* __restrict__ gi, float* __restrict__ gh)
{
    __shared__ char Wb[2][4 * PGW2];
    __shared__ char Ab[2][4 * PLA];

    const int xb = blockIdx.x, bc = blockIdx.y, tid = threadIdx.x;
    const bool isGi = xb < 12;
    const int nbase = (isGi ? xb : xb - 12) * 128;
    const unsigned short* W = isGi ? Wih : Whh;
    float* C = isGi ? gi : gh;

    const int bloc = tid >> 2;
    const int kc   = tid & 3;
    const int b    = bc * 64 + bloc;
    const float* cs = colp + b * Ff;
    const float* mf = m_fix + b * Ff;
    const float azv = isGi ? a_z[b * Nn + Zi] : 0.f;

    uint4 wreg[2];
    uint4 areg;

    auto loadA = [&](int k0) {
        const float* pc = cs + k0 + kc * 8;
        float4 c0 = *(const float4*)pc, c1 = *(const float4*)(pc + 4);
        if (isGi) {
            const float* pm = mf + k0 + kc * 8;
            float4 m0 = *(const float4*)pm, m1 = *(const float4*)(pm + 4);
            areg = pack8(m0.x + azv*c0.x, m0.y + azv*c0.y, m0.z + azv*c0.z, m0.w + azv*c0.w,
                         m1.x + azv*c1.x, m1.y + azv*c1.y, m1.z + azv*c1.z, m1.w + azv*c1.w);
        } else {
            areg = pack8(c0.x, c0.y, c0.z, c0.w, c1.x, c1.y, c1.z, c1.w);
        }
    };

    loadA(0);
#pragma unroll
    for (int i = 0; i < 2; ++i) {
        int chunk = i * 256 + tid;
        wreg[i] = *(const uint4*)(W + (nbase + (chunk >> 2)) * Ff + (chunk & 3) * 8);
    }
#pragma unroll
    for (int i = 0; i < 2; ++i) {
        int chunk = i * 256 + tid;
        *(uint4*)(&Wb[0][(chunk & 3) * PGW2 + (chunk >> 2) * 16]) = wreg[i];
    }
    *(uint4*)(&Ab[0][kc * PLA + bloc * 16]) = areg;
    __syncthreads();

    const int l  = tid & 63;
    const int nw = tid >> 6;
    const int lr = l & 31;
    const int kg = l >> 5;

    f32x16 acc[2];
    acc[0] = (f32x16)(0.f);
    acc[1] = (f32x16)(0.f);

#pragma unroll 1
    for (int ks = 0; ks < 16; ++ks) {
        const int cur = ks & 1;
        if (ks < 15) {
            const int k0 = (ks + 1) * 32;
            loadA(k0);
#pragma unroll
            for (int i = 0; i < 2; ++i) {
                int chunk = i * 256 + tid;
                wreg[i] = *(const uint4*)(W + (nbase + (chunk >> 2)) * Ff + k0 + (chunk & 3) * 8);
            }
        }
#pragma unroll
        for (int s = 0; s < 2; ++s) {
            const int kcv = 2 * s + kg;
            bfrag a0 = *(const bfrag*)(&Ab[cur][kcv * PLA + lr * 16]);
            bfrag a1 = *(const bfrag*)(&Ab[cur][kcv * PLA + (32 + lr) * 16]);
            bfrag bf = *(const bfrag*)(&Wb[cur][kcv * PGW2 + (nw * 32 + lr) * 16]);
            acc[0] = __builtin_amdgcn_mfma_f32_32x32x16_bf16(a0, bf, acc[0], 0, 0, 0);
            acc[1] = __builtin_amdgcn_mfma_f32_32x32x16_bf16(a1, bf, acc[1], 0, 0, 0);
        }
        if (ks < 15) {
#pragma unroll
            for (int i = 0; i < 2; ++i) {
                int chunk = i * 256 + tid;
                *(uint4*)(&Wb[cur ^ 1][(chunk & 3) * PGW2 + (chunk >> 2) * 16]) = wreg[i];
            }
            *(uint4*)(&Ab[cur ^ 1][kc * PLA + bloc * 16]) = areg;
        }
        __syncthreads();
    }

    const int colg = nbase + nw * 32 + lr;
#pragma unroll
    for (int m = 0; m < 2; ++m) {
#pragma unroll
        for (int reg = 0; reg < 16; ++reg) {
            int row = m * 32 + (reg & 3) + 8 * (reg >> 2) + 4 * kg;
            C[(bc * 64 + row) * G3 + colg] = acc[m][reg];
        }
    }
}

// ---------------------------------------------------------------------------
__global__ void gru_kernel(const float* __restrict__ gi, const float* __restrict__ gh,
                           float* __restrict__ col) {
    int idx = blockIdx.x * 256 + threadIdx.x;   // 4 f per thread
    int b = idx >> 7, f = (idx & 127) * 4;
    const float* gib = gi + b * G3;
    const float* ghb = gh + b * G3;
    float4 ir = *(const float4*)(gib + f);
    float4 iz = *(const float4*)(gib + Ff + f);
    float4 in = *(const float4*)(gib + 2 * Ff + f);
    float4 hr = *(const float4*)(ghb + f);
    float4 hz = *(const float4*)(ghb + Ff + f);
    float4 hn = *(const float4*)(ghb + 2 * Ff + f);
    float4 h  = *(const float4*)(col + b * Ff + f);
    float4 o;
#define GRU1(c) { \
    float r = 1.f / (1.f + expf(-(ir.c + hr.c))); \
    float z = 1.f / (1.f + expf(-(iz.c + hz.c))); \
    float n = tanhf(in.c + r * hn.c); \
    o.c = (1.f - z) * n + z * h.c; }
    GRU1(x) GRU1(y) GRU1(z) GRU1(w)
#undef GRU1
    *(float4*)(col + b * Ff + f) = o;
}

// ---------------------------------------------------------------------------
extern "C" void kernel_launch(void* const* d_in, const int* in_sizes, int n_in,
                              void* d_out, int out_size, void* d_ws, size_t ws_size,
                              hipStream_t stream) {
    const float* nf    = (const float*)d_in[0];
    const float* W1    = (const float*)d_in[1];
    const float* b1    = (const float*)d_in[2];
    const float* W2    = (const float*)d_in[3];
    const float* b2    = (const float*)d_in[4];
    const float* w_out = (const float*)d_in[5];
    const float* b_out = (const float*)d_in[6];
    const float* W_ih  = (const float*)d_in[7];
    const float* W_hh  = (const float*)d_in[8];

    float* adj = (float*)d_out;                 // (B, 11, 11)
    float* col = adj + Bsz * Nn * Nn;           // (B, 512)

    unsigned short* W1bf  = (unsigned short*)d_ws;
    unsigned short* W2bf  = W1bf + Ff * Ff;
    unsigned short* Wihbf = W2bf + Ff * Ff;
    unsigned short* Whhbf = Wihbf + G3 * Ff;
    float* a_z   = (float*)(Whhbf + G3 * Ff);
    float* m_fix = a_z + 16384;
    float* gi    = m_fix + Bsz * Ff;
    float* gh    = gi + Bsz * G3;

    init_col_kernel<<<(Bsz * Ff) / 256, 256, 0, stream>>>(nf, col);
    convert_bf16_kernel<<<(Ff * Ff) / 256, 256, 0, stream>>>(W1, W1bf);
    convert_bf16_kernel<<<(Ff * Ff) / 256, 256, 0, stream>>>(W2, W2bf);
    convert_bf16_kernel<<<(G3 * Ff) / 256, 256, 0, stream>>>(W_ih, Wihbf);
    convert_bf16_kernel<<<(G3 * Ff) / 256, 256, 0, stream>>>(W_hh, Whhbf);

    for (int t = 0; t < 3; ++t) {
        const int mode   = (t == 0) ? 0 : 1;
        const int npairs = (t == 0) ? 66 : 11;

        link_kernel<<<npairs * 16, 512, 0, stream>>>(nf, col, W1bf, b1, W2bf, b2,
                                                     w_out, b_out, adj, mode);
        softmax_az_kernel<<<Bsz / 256, 256, 0, stream>>>(adj, a_z);
        mfix_kernel<<<(Bsz * Ff) / 256, 256, 0, stream>>>(nf, a_z, m_fix);

        for (int s = 0; s < 3; ++s) {
            gates_kernel<<<dim3(24, 16), 256, 0, stream>>>(m_fix, a_z, col,
                                                           Wihbf, Whhbf, gi, gh);
            gru_kernel<<<(Bsz * Ff) / 4 / 256, 256, 0, stream>>>(gi, gh, col);
        }
    }
}